// Round 3
// baseline (356.171 us; speedup 1.0000x reference)
//
#include <hip/hip_runtime.h>
#include <math.h>

// Gaussian blur, (64, 512, 512, 3) f32 NHWC, per-batch sigma.
// Reference's kernel k[b,di,dj] depends only on dj (xs broadcast bug in ref),
// so conv = vertical 3-row box sum, then horizontal [w0, w1, w0] over pixels
// (stride 3 floats in channel-interleaved layout).
//   s  = 3*stds[b];  e = exp(-1/s^2)
//   w1 = 1/(3*(1+2e));  w0 = e*w1
//
// V3: barrier-free, LDS-free, wave-autonomous.
//   V2's per-row __syncthreads forced s_waitcnt vmcnt(0) each iteration
//   (compiler drains ALL memory ops before s_barrier), serializing the
//   prefetch load + output store round-trip 32x per block: 126 us at only
//   2.47 TB/s, VALUBusy 7%. Here each lane loads the left/mid/right f4 of
//   each row itself (overlapping dwordx4; extras are L1/L2 hits, no extra
//   HBM), computes the three colsums in registers, and never syncs.
//   Loads pipeline freely 2 rows ahead; roofline ~55-65 us at ~6 TB/s.

constexpr int Wd     = 512;
constexpr int Hd     = 512;
constexpr int Cd     = 3;
constexpr int ROWF   = Wd * Cd;        // 1536 floats per row
constexpr int TPB    = ROWF / 4;       // 384 threads, one f4 column each
constexpr int RPB    = 32;             // rows per block
constexpr int STRIPS = Hd / RPB;       // 16 strips per image

using f4 = __attribute__((ext_vector_type(4))) float;

__device__ __forceinline__ f4 f4z() { return (f4){0.f, 0.f, 0.f, 0.f}; }

__global__ __launch_bounds__(TPB) void gauss_wave_kernel(
    const float* __restrict__ x,
    const float* __restrict__ stds,
    float* __restrict__ out)
{
    const int t = threadIdx.x;
    const int s = blockIdx.x % STRIPS;  // strip index within image
    const int b = blockIdx.x / STRIPS;  // batch

    const float sg = stds[b] * 3.0f;
    const float e  = expf(-1.0f / (sg * sg));
    const float w1 = 1.0f / (3.0f * (1.0f + 2.0f * e));
    const float w0 = e * w1;

    const size_t imgbase = (size_t)b * Hd * ROWF;
    const float* px = x   + imgbase + (size_t)t * 4;
    float*       po = out + imgbase + (size_t)t * 4;

    // horizontal zero-padding: first f4 of the row has no left neighbor,
    // last f4 has no right neighbor. Clamp the address (avoid OOB), zero the
    // contribution via a 0/1 mask on the final colsum.
    const bool  hasL  = (t > 0);
    const bool  hasR  = (t < TPB - 1);
    const int   offL  = hasL ? -4 : 0;
    const int   offR  = hasR ? +4 : 0;
    const float maskL = hasL ? 1.f : 0.f;
    const float maskR = hasR ? 1.f : 0.f;

    const int r0 = s * RPB;

    // rolling 3-row window of (left, mid, right) f4 loads; rows a=j-1, b=j, c=j+1
    f4 La, Ma, Ra, Lb, Mb, Rb, Lc, Mc, Rc;

    auto loadrow = [&](int j, f4& L, f4& M, f4& R) {
        if (j < 0 || j >= Hd) { L = f4z(); M = f4z(); R = f4z(); return; }
        const float* rp = px + (size_t)j * ROWF;
        L = *(const f4*)(rp + offL);
        M = *(const f4*)(rp);
        R = *(const f4*)(rp + offR);
    };

    loadrow(r0 - 1, La, Ma, Ra);
    loadrow(r0,     Lb, Mb, Rb);
    loadrow(r0 + 1, Lc, Mc, Rc);

    #pragma unroll 4
    for (int j = r0; j < r0 + RPB; ++j) {
        // prefetch row j+2 (consumed next iteration; no barrier in between)
        f4 Ln, Mn, Rn;
        loadrow(j + 2, Ln, Mn, Rn);

        // vertical 3-row colsums for left / mid / right f4 positions
        f4 m  = Ma + Mb + Mc;
        f4 pL = (La + Lb + Lc) * maskL;   // colsum[f-4 .. f-1]
        f4 nR = (Ra + Rb + Rc) * maskR;   // colsum[f+4 .. f+7]

        // out[f+k] = w1*colsum[f+k] + w0*(colsum[f+k-3] + colsum[f+k+3])
        f4 o;
        o.x = w1 * m.x + w0 * (pL.y + m.w);
        o.y = w1 * m.y + w0 * (pL.z + nR.x);
        o.z = w1 * m.z + w0 * (pL.w + nR.y);
        o.w = w1 * m.w + w0 * (m.x + nR.z);

        __builtin_nontemporal_store(o, (f4*)(po + (size_t)j * ROWF));

        La = Lb; Lb = Lc; Lc = Ln;
        Ma = Mb; Mb = Mc; Mc = Mn;
        Ra = Rb; Rb = Rc; Rc = Rn;
    }
}

extern "C" void kernel_launch(void* const* d_in, const int* in_sizes, int n_in,
                              void* d_out, int out_size, void* d_ws, size_t ws_size,
                              hipStream_t stream) {
    const float* x    = (const float*)d_in[0];
    const float* stds = (const float*)d_in[1];
    float* out        = (float*)d_out;

    const int nblocks = 64 * STRIPS;   // one block per (batch, 32-row strip) = 1024
    gauss_wave_kernel<<<nblocks, TPB, 0, stream>>>(x, stds, out);
}

// Round 4
// 332.582 us; speedup vs baseline: 1.0709x; 1.0709x over previous
//
#include <hip/hip_runtime.h>
#include <math.h>

// Gaussian blur, (64, 512, 512, 3) f32 NHWC, per-batch sigma.
// Reference's kernel k[b,di,dj] depends only on dj (xs broadcast bug in ref),
// so conv = vertical 3-row box sum, then horizontal [w0, w1, w0] over pixels
// (stride 3 floats in channel-interleaved layout).
//   s  = 3*stds[b];  e = exp(-1/s^2)
//   w1 = 1/(3*(1+2e));  w0 = e*w1
//
// V4: burst-staged LDS, copy-style global access.
//   V1 (LDS+barrier/row) 115us, V2 (strip+barrier) 126us, V3 (regs, no
//   barrier) 133us -- all stuck at 2.3-2.7 TB/s because global loads sat on
//   the compute loop's critical path (small reg window -> few outstanding
//   loads), while fill=6.7 TB/s and float4 copy=6.3 TB/s on this chip.
//   Here each block stages 6 rows (4 output + 2 halo) as one burst of 6
//   independent dwordx4 loads -> LDS (zero-padded columns), ONE barrier,
//   then computes 4 rows purely from LDS and streams nontemporal stores.
//   Global pattern == copy kernel. 8192 blocks (4/CU by LDS, 24 waves/CU),
//   bijective XCD swizzle for halo L2 locality. Roofline ~70us @ ~6 TB/s.

constexpr int Wd     = 512;
constexpr int Hd     = 512;
constexpr int Cd     = 3;
constexpr int ROWF   = Wd * Cd;          // 1536 floats per image row
constexpr int TPB    = ROWF / 4;         // 384 threads, one f4 column each
constexpr int G      = 4;                // output rows per block
constexpr int SR     = G + 2;            // staged rows (with vertical halo)
constexpr int LROW   = ROWF + 8;         // 1544 floats: [0..3]=left pad, [4..1539]=data, [1540..1543]=right pad
constexpr int GP_IMG = Hd / G;           // 128 row-groups per image
constexpr int NB     = 64 * GP_IMG;      // 8192 blocks

using f4 = __attribute__((ext_vector_type(4))) float;

__device__ __forceinline__ f4 f4z() { return (f4){0.f, 0.f, 0.f, 0.f}; }

__global__ __launch_bounds__(TPB) void gauss_stage_kernel(
    const float* __restrict__ x,
    const float* __restrict__ stds,
    float* __restrict__ out)
{
    __shared__ float lds[SR * LROW];     // 6 * 1544 * 4 B = 37,056 B

    const int t = threadIdx.x;

    // bijective XCD swizzle (NB % 8 == 0): each XCD gets a contiguous chunk
    // of (image, group) work so adjacent strips' halo rows share its L2.
    const int bid = blockIdx.x;
    const int swz = (bid & 7) * (NB / 8) + (bid >> 3);
    const int b   = swz >> 7;            // / GP_IMG
    const int g   = swz & (GP_IMG - 1);
    const int r0  = g * G;

    const float sg = stds[b] * 3.0f;
    const float e  = expf(-1.0f / (sg * sg));
    const float w1 = 1.0f / (3.0f * (1.0f + 2.0f * e));
    const float w0 = e * w1;

    const float* img = x + (size_t)b * Hd * ROWF;

    // ---- stage: burst of SR independent global loads, then LDS writes ----
    f4 st[SR];
    #pragma unroll
    for (int i = 0; i < SR; ++i) {
        const int row = r0 - 1 + i;       // vertical zero halo at image edges
        st[i] = (row >= 0 && row < Hd)
              ? *(const f4*)(img + (size_t)row * ROWF + 4 * t)
              : f4z();
    }
    #pragma unroll
    for (int i = 0; i < SR; ++i)
        *(f4*)(&lds[i * LROW + 4 + 4 * t]) = st[i];

    // horizontal zero pads (one f4 each side per staged row)
    if (t < SR)              *(f4*)(&lds[t * LROW]) = f4z();
    else if (t < 2 * SR)     *(f4*)(&lds[(t - SR) * LROW + 4 + ROWF]) = f4z();

    __syncthreads();

    // ---- compute: pure-LDS stencil, nontemporal streaming stores ----
    float* po = out + (size_t)b * Hd * ROWF + 4 * t;

    #pragma unroll
    for (int j = 0; j < G; ++j) {
        const float* b0 = &lds[(j + 0) * LROW + 4 * t];
        const float* b1 = &lds[(j + 1) * LROW + 4 * t];
        const float* b2 = &lds[(j + 2) * LROW + 4 * t];

        f4 p = *(const f4*)(b0)     + *(const f4*)(b1)     + *(const f4*)(b2);     // colsum @ col t-1
        f4 m = *(const f4*)(b0 + 4) + *(const f4*)(b1 + 4) + *(const f4*)(b2 + 4); // colsum @ col t
        f4 n = *(const f4*)(b0 + 8) + *(const f4*)(b1 + 8) + *(const f4*)(b2 + 8); // colsum @ col t+1

        // out[f+k] = w1*colsum[f+k] + w0*(colsum[f+k-3] + colsum[f+k+3])
        f4 o;
        o.x = w1 * m.x + w0 * (p.y + m.w);
        o.y = w1 * m.y + w0 * (p.z + n.x);
        o.z = w1 * m.z + w0 * (p.w + n.y);
        o.w = w1 * m.w + w0 * (m.x + n.z);

        __builtin_nontemporal_store(o, (f4*)(po + (size_t)(r0 + j) * ROWF));
    }
}

extern "C" void kernel_launch(void* const* d_in, const int* in_sizes, int n_in,
                              void* d_out, int out_size, void* d_ws, size_t ws_size,
                              hipStream_t stream) {
    const float* x    = (const float*)d_in[0];
    const float* stds = (const float*)d_in[1];
    float* out        = (float*)d_out;

    gauss_stage_kernel<<<NB, TPB, 0, stream>>>(x, stds, out);
}